// Round 8
// baseline (133.136 us; speedup 1.0000x reference)
//
#include <hip/hip_runtime.h>
#include <cmath>

#define BB  4
#define VV  4096
#define KK  40
#define FIN 64

typedef float v2f __attribute__((ext_vector_type(2)));

// ---------------------------------------------------------------------------
// Kernel A: 4 rows per wave (unchanged).
// ---------------------------------------------------------------------------
__global__ __launch_bounds__(256) void prep_kernel(
    const float* __restrict__ x, const float* __restrict__ Wf,
    const float* __restrict__ bf, const float* __restrict__ Ws,
    const float* __restrict__ bs,
    float* __restrict__ coords, float* __restrict__ sq,
    float* __restrict__ feats)
{
    int lane = threadIdx.x & 63;
    int wid  = threadIdx.x >> 6;
    int row0 = (blockIdx.x * 4 + wid) * 4;        // 4 rows per wave
    const float* xr = x + (size_t)row0 * FIN;

    float a0 = 0.f, a1 = 0.f, a2 = 0.f, a3 = 0.f;
    #pragma unroll 8
    for (int k = 0; k < FIN; ++k) {
        float wf = Wf[k * 64 + lane];              // one coalesced 256B row
        a0 = fmaf(xr[k],        wf, a0);           // x: wave-uniform loads
        a1 = fmaf(xr[64  + k],  wf, a1);
        a2 = fmaf(xr[128 + k],  wf, a2);
        a3 = fmaf(xr[192 + k],  wf, a3);
    }
    float bfl = bf[lane];
    feats[(size_t)(row0 + 0) * 64 + lane] = a0 + bfl;
    feats[(size_t)(row0 + 1) * 64 + lane] = a1 + bfl;
    feats[(size_t)(row0 + 2) * 64 + lane] = a2 + bfl;
    feats[(size_t)(row0 + 3) * 64 + lane] = a3 + bfl;

    // coords + sq for the same 4 rows
    int r  = lane >> 4;                            // 0..3 row
    int s  = (lane >> 2) & 3;                      // 0..3 coord dim
    int kc = lane & 3;                             // 0..3 k-chunk
    const float* xrr = x + (size_t)(row0 + r) * FIN + kc * 16;
    const float* wsr = Ws + kc * 16 * 4 + s;
    float c = 0.f;
    #pragma unroll
    for (int k = 0; k < 16; ++k)
        c = fmaf(xrr[k], wsr[k * 4], c);
    c += __shfl_xor(c, 1, 64);                     // reduce over kc
    c += __shfl_xor(c, 2, 64);
    float val = c + bs[s];
    if ((lane & 3) == 0) coords[(size_t)(row0 + r) * 4 + s] = val;
    float p = val * val;
    p += __shfl_xor(p, 4, 64);                     // reduce over s
    p += __shfl_xor(p, 8, 64);
    if ((lane & 15) == 0) sq[row0 + r] = p;
}

// ---------------------------------------------------------------------------
// Kernel B: one wave per TWO consecutive queries (same batch: 2 | 4096).
//   Round-7 lesson: 4 q/wave gave only 4 waves/SIMD -> latency-bound
//   (VALUBusy 63%). 2 q/wave doubles wave-level latency hiding (8/SIMD,
//   __launch_bounds__(256,8) caps VGPR at 64) at ~5% more total issue.
//   Distance core: ONE VMEM stream (cb[u] float4); squ recomputed in 4
//   shared VALU ops (drops the dependent sqb[u] load). The 2 queries pack
//   exactly one v2f chain: d2 = (sqv + squ) + dot(-2cq, cu) via pk_fma.
//   Depth-2 insertion network; 31-step ballot radix select (VALU cost =
//   4 v_cmp per query per bit, count/select on SALU); robust rank-0 drop
//   via shfl butterfly; compact pre-decodes {u*256, exp(-10*d2)} so the
//   gather is ds_read_b64 + add + load + mul/max/add.
//   No __syncthreads: all LDS use is same-wave.
// ---------------------------------------------------------------------------
__global__ __launch_bounds__(256, 8) void gravnet_kernel(
    const float* __restrict__ x, const float* __restrict__ coords,
    const float* __restrict__ sq, const float* __restrict__ feats,
    const float* __restrict__ Wo, const float* __restrict__ bo,
    float* __restrict__ out)
{
    int lane = threadIdx.x & 63;
    int wid  = threadIdx.x >> 6;
    int q0   = (blockIdx.x * 4 + wid) * 2;        // first of 2 queries
    int b    = q0 >> 12;
    int v0   = q0 & (VV - 1);

    __shared__ uint2               s_nb[4][2][KK];   // {u*256, bits(w)}
    __shared__ __align__(16) float s_upd[4][2][192];

    const float4* cb  = (const float4*)(coords + (size_t)b * VV * 4);
    const float*  sqb = sq + (size_t)b * VV;

    // pair-packed query constants: n* = -2*cq, hs = sqv  (lane-uniform)
    float4 cqa = cb[v0], cqb = cb[v0 + 1];
    v2f nx = (v2f){-2.f * cqa.x, -2.f * cqb.x};
    v2f ny = (v2f){-2.f * cqa.y, -2.f * cqb.y};
    v2f nz = (v2f){-2.f * cqa.z, -2.f * cqb.z};
    v2f nw = (v2f){-2.f * cqa.w, -2.f * cqb.w};
    v2f hs = (v2f){sqb[v0], sqb[v0 + 1]};

    // --- distance + key + per-lane top-4 for 2 queries
    unsigned mm[2][4];
    #pragma unroll
    for (int qq = 0; qq < 2; ++qq)
        mm[qq][0] = mm[qq][1] = mm[qq][2] = mm[qq][3] = 0xFFFFFFFFu;

    #pragma unroll 4
    for (int i = 0; i < 64; ++i) {
        int u = i * 64 + lane;
        float4 cu = cb[u];                         // the only VMEM stream
        float squ = cu.x * cu.x;                   // recomputed, shared
        squ = fmaf(cu.y, cu.y, squ);
        squ = fmaf(cu.z, cu.z, squ);
        squ = fmaf(cu.w, cu.w, squ);
        v2f acc = hs + (v2f){squ, squ};            // pk_add
        acc = __builtin_elementwise_fma(nx, (v2f){cu.x, cu.x}, acc);
        acc = __builtin_elementwise_fma(ny, (v2f){cu.y, cu.y}, acc);
        acc = __builtin_elementwise_fma(nz, (v2f){cu.z, cu.z}, acc);
        acc = __builtin_elementwise_fma(nw, (v2f){cu.w, cu.w}, acc);
        float d2s[2] = { acc.x, acc.y };
        #pragma unroll
        for (int qq = 0; qq < 2; ++qq) {
            float d2 = fmaxf(d2s[qq], 0.f);        // keys non-negative
            unsigned key = (__float_as_uint(d2) & 0xFFFFF000u) | (unsigned)u;
            // depth-2 insert into sorted m0<=m1<=m2<=m3
            unsigned b0 = max(mm[qq][0], key);
            unsigned b1 = max(mm[qq][1], key);
            unsigned b2 = max(mm[qq][2], key);
            mm[qq][0] = min(mm[qq][0], key);
            mm[qq][1] = min(mm[qq][1], b0);
            mm[qq][2] = min(mm[qq][2], b1);
            mm[qq][3] = min(mm[qq][3], b2);
        }
    }

    // --- radix-select rank-39 key M per query (bit 31 always 0)
    unsigned M[2] = {0u, 0u};
    for (int bit = 30; bit >= 0; --bit) {
        #pragma unroll
        for (int qq = 0; qq < 2; ++qq) {
            unsigned cand = M[qq] | (1u << bit);
            int cnt = (int)__popcll(__ballot(mm[qq][0] < cand))
                    + (int)__popcll(__ballot(mm[qq][1] < cand))
                    + (int)__popcll(__ballot(mm[qq][2] < cand))
                    + (int)__popcll(__ballot(mm[qq][3] < cand));
            if (cnt <= 39) M[qq] = cand;
        }
    }

    // --- per query: drop rank-0 (global min, robust) + compact 39 to LDS
    #pragma unroll
    for (int qq = 0; qq < 2; ++qq) {
        unsigned mn = mm[qq][0];
        #pragma unroll
        for (int off = 32; off >= 1; off >>= 1) {
            unsigned o = __shfl_xor(mn, off, 64);
            mn = o < mn ? o : mn;
        }
        int base = 0;
        #pragma unroll
        for (int i = 0; i < 4; ++i) {
            unsigned kk = mm[qq][i];
            bool pred = (kk <= M[qq]) && (kk != mn);
            unsigned long long mask = __ballot(pred);
            unsigned pos = (unsigned)base +
                __builtin_amdgcn_mbcnt_hi((unsigned)(mask >> 32),
                    __builtin_amdgcn_mbcnt_lo((unsigned)mask, 0u));
            if (pred) {
                float d2a = __uint_as_float(kk & 0xFFFFF000u);
                float w   = __expf(-10.f * d2a);
                s_nb[wid][qq][pos] =
                    make_uint2((kk & 4095u) << 8, __float_as_uint(w));
            }
            base += (int)__popcll(mask);
        }
    }
    // same-wave LDS write->read: no barrier needed

    // --- gather 39 neighbours x 2 queries, weighted max + sum
    const float* fb  = feats + (size_t)b * VV * 64;
    const char*  fbl = (const char*)(fb + lane);   // lane offset baked in
    float vmax[2], vsum[2];
    #pragma unroll
    for (int qq = 0; qq < 2; ++qq) { vmax[qq] = -INFINITY; vsum[qq] = 0.f; }
    #pragma unroll 6
    for (int j = 0; j < KK - 1; ++j) {
        #pragma unroll
        for (int qq = 0; qq < 2; ++qq) {
            uint2 nb = s_nb[wid][qq][j];           // ds_read_b64
            float f  = *(const float*)(fbl + nb.x);
            float w  = __uint_as_float(nb.y);
            float val = w * f;
            vmax[qq] = fmaxf(vmax[qq], val);
            vsum[qq] += val;
        }
    }

    // --- updated vectors to LDS
    #pragma unroll
    for (int qq = 0; qq < 2; ++qq) {
        s_upd[wid][qq][lane]       = x[(size_t)(q0 + qq) * 64 + lane];
        s_upd[wid][qq][64  + lane] = vmax[qq];
        s_upd[wid][qq][128 + lane] = vsum[qq] * (1.0f / 39.0f);
    }

    // --- GEMV (192 x 64) x 2: Wo row loaded once, 2 fma each
    float bol = bo[lane];
    float acc0 = bol, acc1 = bol;
    #pragma unroll 4
    for (int j4 = 0; j4 < 48; ++j4) {
        float wo0 = Wo[(j4 * 4 + 0) * 64 + lane];
        float wo1 = Wo[(j4 * 4 + 1) * 64 + lane];
        float wo2 = Wo[(j4 * 4 + 2) * 64 + lane];
        float wo3 = Wo[(j4 * 4 + 3) * 64 + lane];
        float4 u0 = *(const float4*)&s_upd[wid][0][j4 * 4]; // LDS bcast
        float4 u1 = *(const float4*)&s_upd[wid][1][j4 * 4];
        acc0 = fmaf(u0.x, wo0, acc0);  acc1 = fmaf(u1.x, wo0, acc1);
        acc0 = fmaf(u0.y, wo1, acc0);  acc1 = fmaf(u1.y, wo1, acc1);
        acc0 = fmaf(u0.z, wo2, acc0);  acc1 = fmaf(u1.z, wo2, acc1);
        acc0 = fmaf(u0.w, wo3, acc0);  acc1 = fmaf(u1.w, wo3, acc1);
    }
    float e0 = __expf(2.f * acc0);                 // tanh = 1 - 2/(e^2x+1)
    float e1 = __expf(2.f * acc1);
    out[(size_t)q0 * 64 + lane]       = 1.f - __fdividef(2.f, e0 + 1.f);
    out[(size_t)(q0 + 1) * 64 + lane] = 1.f - __fdividef(2.f, e1 + 1.f);
}

// ---------------------------------------------------------------------------
extern "C" void kernel_launch(void* const* d_in, const int* in_sizes, int n_in,
                              void* d_out, int out_size, void* d_ws, size_t ws_size,
                              hipStream_t stream)
{
    (void)in_sizes; (void)n_in; (void)out_size; (void)ws_size;
    const float* x  = (const float*)d_in[0];
    const float* Wf = (const float*)d_in[1];
    const float* bf = (const float*)d_in[2];
    const float* Ws = (const float*)d_in[3];
    const float* bs = (const float*)d_in[4];
    const float* Wo = (const float*)d_in[5];
    const float* bo = (const float*)d_in[6];
    float* out = (float*)d_out;

    float* coords = (float*)d_ws;                     // B*V*4  floats (256 KB)
    float* sq     = coords + (size_t)BB * VV * 4;     // B*V    floats (64 KB)
    float* feats  = sq + (size_t)BB * VV;             // B*V*64 floats (4 MB)

    prep_kernel<<<BB * VV / 16, 256, 0, stream>>>(x, Wf, bf, Ws, bs,
                                                  coords, sq, feats);
    gravnet_kernel<<<BB * VV / 8, 256, 0, stream>>>(x, coords, sq, feats,
                                                    Wo, bo, out);
}